// Round 13
// baseline (171.708 us; speedup 1.0000x reference)
//
#include <hip/hip_runtime.h>
#include <hip/hip_bf16.h>

typedef _Float16 f16x8  __attribute__((ext_vector_type(8)));
typedef _Float16 f16x16 __attribute__((ext_vector_type(16)));
typedef float    f32x16 __attribute__((ext_vector_type(16)));
typedef float    v2f    __attribute__((ext_vector_type(2)));
typedef unsigned u32x4  __attribute__((ext_vector_type(4)));

__device__ __forceinline__ unsigned pk16(float a, float b) {
    return __builtin_bit_cast(unsigned, __builtin_amdgcn_cvt_pkrtz(a, b));
}

// Padé[5/6] tanh kernel (Gauss continued fraction, depth 6), packed 2-wide.
// tanh(u) ~= N/D, N = u(10395 + 1260u^2 + 21u^4), D = 10395 + 4725u^2 + 210u^4 + u^6
// max err 9.8e-4 on [-5,5] (2.2e-5 at |u|=3); inputs clamped to [-5,5].
// Pure packed FMAs -> moves gate activations off the (saturated) trans pipe.
__device__ __forceinline__ void tk2(v2f u, v2f& N, v2f& D) {
    const v2f c5 = { 5.0f, 5.0f }, cm5 = { -5.0f, -5.0f };
    u = __builtin_elementwise_max(u, cm5);
    u = __builtin_elementwise_min(u, c5);
    const v2f y = u * u;
    v2f n = __builtin_elementwise_fma((v2f){21.0f, 21.0f}, y, (v2f){1260.0f, 1260.0f});
    n = __builtin_elementwise_fma(n, y, (v2f){10395.0f, 10395.0f});
    N = u * n;
    v2f d = y + (v2f){210.0f, 210.0f};
    d = __builtin_elementwise_fma(d, y, (v2f){4725.0f, 4725.0f});
    D = __builtin_elementwise_fma(d, y, (v2f){10395.0f, 10395.0f});
}

// r12 structure (64 rows/wave, grid-stride 4 tiles/block, rolled t-loop, (256,3));
// activations rebuilt on rational tanh: sigma(x) = (D+N)/(2D) at u=x/2 (weights
// prescaled 0.5; g-gate rows 1.0), c in NATURAL domain.
// c' = f*c + i*g = [Pf*c*DiDg + Pi*Ng*Df] / (2*Df*Di*Dg)  -> ONE rcp (pair-shared 2)
// h  = sigma(go)*tanh(c') = Po*Nc / (2*Do*Dc)              -> ONE rcp (pair-shared 2)
// trans/unit-step: 6 -> 1 (zero exp2). Fitted model dur = 40us + 0.129us*trans.
__global__ __launch_bounds__(256, 3) void lstm_mfma_kernel(
    const float* __restrict__ mobility,  // [B,7]
    const float* __restrict__ controls,  // [B,5]
    const float* __restrict__ W_cc, const float* __restrict__ b_cc,
    const float* __restrict__ W_ih, const float* __restrict__ W_hh,
    const float* __restrict__ b_ih, const float* __restrict__ b_hh,
    const float* __restrict__ W1,  const float* __restrict__ b1,
    const float* __restrict__ W2,  const float* __restrict__ b2,
    const float* __restrict__ W3,  const float* __restrict__ b3,
    float* __restrict__ out, int Btot)
{
    __shared__ float hbuf[256][17];   // stride-17: conflict-free

    const int tid  = threadIdx.x;
    const int lane = tid & 63;
    const int wib  = tid >> 6;
    const int col  = lane & 31;
    const int hi   = lane >> 5;

    // ---- weights once per block; prescale: i,f,o rows 0.5 ; g rows 1.0 ----
    f16x8 afrag[2];
    #pragma unroll
    for (int gb = 0; gb < 2; ++gb) {
        const float s = (gb == 0) ? 0.5f : ((col < 16) ? 1.0f : 0.5f);
        const float* wr = W_hh + (gb * 32 + col) * 16 + hi * 8;
        u32x4 aw = { pk16(s * wr[0], s * wr[1]), pk16(s * wr[2], s * wr[3]),
                     pk16(s * wr[4], s * wr[5]), pk16(s * wr[6], s * wr[7]) };
        afrag[gb] = __builtin_bit_cast(f16x8, aw);
    }
    f16x16 bias_h[2], wih_h[2];
    #pragma unroll
    for (int gb = 0; gb < 2; ++gb)
        #pragma unroll
        for (int q = 0; q < 4; ++q) {
            const int gu = gb * 32 + 8 * q + 4 * hi;
            const float s = (gu < 32) ? 0.5f : ((gu < 48) ? 1.0f : 0.5f);
            #pragma unroll
            for (int e = 0; e < 4; ++e) {
                bias_h[gb][4 * q + e] = (_Float16)(s * (b_ih[gu + e] + b_hh[gu + e]));
                wih_h [gb][4 * q + e] = (_Float16)(s * W_ih[gu + e]);
            }
        }

    const int tilesTotal = (Btot + 255) >> 8;      // 4096
    for (int tile = blockIdx.x; tile < tilesTotal; tile += gridDim.x) {
        const int blockRow0 = tile * 256;
        const int r_lo = blockRow0 + wib * 64 + col;
        const int r_hi = r_lo + 32;

        float mlo[7], mhi[7];
        #pragma unroll
        for (int t = 0; t < 7; ++t) { mlo[t] = mobility[(size_t)r_lo * 7 + t]; mhi[t] = mobility[(size_t)r_hi * 7 + t]; }

        float c[2][8];
        #pragma unroll
        for (int rb = 0; rb < 2; ++rb)
            #pragma unroll
            for (int u = 0; u < 8; ++u) c[rb][u] = 0.0f;

        u32x4 bz = { 0u, 0u, 0u, 0u };
        f16x8 bfrag[2];
        bfrag[0] = __builtin_bit_cast(f16x8, bz);
        bfrag[1] = __builtin_bit_cast(f16x8, bz);

        #pragma unroll 1   // rolled: keeps live ranges small (r7 lesson)
        for (int t = 0; t < 7; ++t) {
            #pragma unroll
            for (int rb = 0; rb < 2; ++rb) {
                const float xt = rb ? mhi[t] : mlo[t];

                f32x16 cin0, cin1;
                #pragma unroll
                for (int r = 0; r < 16; ++r)
                    cin0[r] = fmaf(xt, (float)wih_h[0][r], (float)bias_h[0][r]);  // fma_mix
                f32x16 a0 = __builtin_amdgcn_mfma_f32_32x32x16_f16(afrag[0], bfrag[rb], cin0, 0, 0, 0);
                #pragma unroll
                for (int r = 0; r < 16; ++r)
                    cin1[r] = fmaf(xt, (float)wih_h[1][r], (float)bias_h[1][r]);
                f32x16 a1 = __builtin_amdgcn_mfma_f32_32x32x16_f16(afrag[1], bfrag[rb], cin1, 0, 0, 0);

                // a0[u]=gi/2, a0[u+8]=gf/2, a1[u]=gg, a1[u+8]=go/2
                float h[8];
                #pragma unroll
                for (int u = 0; u < 8; u += 2) {
                    v2f ui = { a0[u], a0[u + 1] };
                    v2f uf = { a0[u + 8], a0[u + 9] };
                    v2f ug = { a1[u], a1[u + 1] };
                    v2f Ni, Di, Nf, Df, Ng, Dg;
                    tk2(ui, Ni, Di); const v2f Pi = Di + Ni;   // 2D*sigma(gi)
                    tk2(uf, Nf, Df); const v2f Pf = Df + Nf;
                    tk2(ug, Ng, Dg);

                    const v2f cv = { c[rb][u], c[rb][u + 1] };
                    const v2f DiDg = Di * Dg;
                    const v2f Q = DiDg * Df;
                    const v2f numer = __builtin_elementwise_fma(Pi * Ng, Df, (Pf * cv) * DiDg);
                    const float rQ = 0.5f * __builtin_amdgcn_rcpf(Q[0] * Q[1]);
                    const v2f Qsw = { Q[1], Q[0] };
                    const v2f cs = (numer * Qsw) * (v2f){ rQ, rQ };
                    c[rb][u]     = cs[0];
                    c[rb][u + 1] = cs[1];

                    v2f uo = { a1[u + 8], a1[u + 9] };
                    v2f No, Do; tk2(uo, No, Do); const v2f Po = Do + No;
                    v2f Nc, Dc; tk2(cs, Nc, Dc);
                    const v2f R = Do * Dc;
                    const float rR = 0.5f * __builtin_amdgcn_rcpf(R[0] * R[1]);
                    const v2f Rsw = { R[1], R[0] };
                    const v2f hv = ((Po * Nc) * Rsw) * (v2f){ rR, rR };
                    h[u]     = hv[0];
                    h[u + 1] = hv[1];
                }
                unsigned q0 = pk16(h[0], h[1]);
                unsigned q1 = pk16(h[2], h[3]);
                unsigned q2 = pk16(h[4], h[5]);
                unsigned q3 = pk16(h[6], h[7]);
                auto s02 = __builtin_amdgcn_permlane32_swap(q0, q2, false, false);
                auto s13 = __builtin_amdgcn_permlane32_swap(q1, q3, false, false);
                u32x4 bw = { s02[0], s13[0], s02[1], s13[1] };
                bfrag[rb] = __builtin_bit_cast(f16x8, bw);
            }
        }

        // ---- final h straight from bfrag (lane holds units hi*8+e of its col) ----
        #pragma unroll
        for (int rb = 0; rb < 2; ++rb) {
            const int rr = wib * 64 + col + rb * 32;
            #pragma unroll
            for (int e = 0; e < 8; ++e)
                hbuf[rr][hi * 8 + e] = (float)bfrag[rb][e];
        }
        __syncthreads();

        // ---- fc stage: thread tid owns tile-local row tid ----
        const int grow = blockRow0 + tid;

        float x19[19];
        #pragma unroll
        for (int k = 0; k < 16; ++k) x19[k] = hbuf[tid][k];

        float ctl[5];
        #pragma unroll
        for (int k = 0; k < 5; ++k) ctl[k] = controls[(size_t)grow * 5 + k];
        #pragma unroll
        for (int j = 0; j < 3; ++j) {
            float a = b_cc[j];
            #pragma unroll
            for (int k = 0; k < 5; ++k) a = fmaf(ctl[k], W_cc[j * 5 + k], a);
            x19[16 + j] = a;
        }

        // fc1: Linear(19->16) + rational tanh, pair-merged rcp
        v2f t12[8];
        #pragma unroll
        for (int j = 0; j < 16; j += 2) {
            float aa[2];
            #pragma unroll
            for (int jj = 0; jj < 2; ++jj) {
                float a = b1[j + jj];
                #pragma unroll
                for (int k = 0; k < 19; ++k) a = fmaf(x19[k], W1[(j + jj) * 19 + k], a);
                aa[jj] = a;
            }
            v2f av = { aa[0], aa[1] };
            v2f N, D; tk2(av, N, D);
            const float rP = __builtin_amdgcn_rcpf(D[0] * D[1]);
            const v2f Dsw = { D[1], D[0] };
            t12[j >> 1] = (N * Dsw) * (v2f){ rP, rP };
        }

        // fc2: Linear(16->16) + rational tanh (packed fma, pair-merged rcp)
        v2f t22[8];
        #pragma unroll
        for (int j = 0; j < 16; j += 2) {
            float aa[2];
            #pragma unroll
            for (int jj = 0; jj < 2; ++jj) {
                const v2f* w2row = (const v2f*)(W2 + (j + jj) * 16);
                v2f a = t12[0] * w2row[0];
                #pragma unroll
                for (int p = 1; p < 8; ++p) a = __builtin_elementwise_fma(t12[p], w2row[p], a);
                aa[jj] = a.x + a.y + b2[j + jj];
            }
            v2f av = { aa[0], aa[1] };
            v2f N, D; tk2(av, N, D);
            const float rP = __builtin_amdgcn_rcpf(D[0] * D[1]);
            const v2f Dsw = { D[1], D[0] };
            t22[j >> 1] = (N * Dsw) * (v2f){ rP, rP };
        }

        // fc3: Linear(16->1) + ReLU
        const v2f* w3p = (const v2f*)W3;
        v2f a3 = t22[0] * w3p[0];
        #pragma unroll
        for (int p = 1; p < 8; ++p) a3 = __builtin_elementwise_fma(t22[p], w3p[p], a3);
        const float r = a3.x + a3.y + b3[0];
        if (grow < Btot) out[grow] = fmaxf(r, 0.0f);

        __syncthreads();   // protect hbuf against next tile's writes
    }
}

extern "C" void kernel_launch(void* const* d_in, const int* in_sizes, int n_in,
                              void* d_out, int out_size, void* d_ws, size_t ws_size,
                              hipStream_t stream) {
    const float* mobility = (const float*)d_in[0];
    const float* controls = (const float*)d_in[1];
    // d_in[2] = last : unused by the reference
    const float* W_cc = (const float*)d_in[3];
    const float* b_cc = (const float*)d_in[4];
    const float* W_ih = (const float*)d_in[5];
    const float* W_hh = (const float*)d_in[6];
    const float* b_ih = (const float*)d_in[7];
    const float* b_hh = (const float*)d_in[8];
    const float* W1   = (const float*)d_in[9];
    const float* b1   = (const float*)d_in[10];
    const float* W2   = (const float*)d_in[11];
    const float* b2   = (const float*)d_in[12];
    const float* W3   = (const float*)d_in[13];
    const float* b3   = (const float*)d_in[14];
    float* out = (float*)d_out;

    const int Btot  = in_sizes[0] / 7;              // 1048576
    const int tiles = (Btot + 255) / 256;           // 4096
    const int grid  = tiles < 1024 ? tiles : 1024;  // 4 tiles/block

    lstm_mfma_kernel<<<grid, 256, 0, stream>>>(
        mobility, controls, W_cc, b_cc, W_ih, W_hh, b_ih, b_hh,
        W1, b1, W2, b2, W3, b3, out, Btot);
}

// Round 14
// 103.457 us; speedup vs baseline: 1.6597x; 1.6597x over previous
//
#include <hip/hip_runtime.h>
#include <hip/hip_bf16.h>

typedef _Float16 f16x8  __attribute__((ext_vector_type(8)));
typedef float    f32x16 __attribute__((ext_vector_type(16)));
typedef float    v2f    __attribute__((ext_vector_type(2)));
typedef unsigned u32x4  __attribute__((ext_vector_type(4)));

#define LOG2E 1.442695040888963f

__device__ __forceinline__ unsigned pk16(float a, float b) {
    return __builtin_bit_cast(unsigned, __builtin_amdgcn_cvt_pkrtz(a, b));
}
__device__ __forceinline__ float fexp2(float x) { return __builtin_amdgcn_exp2f(x); }
__device__ __forceinline__ float frcp(float x)  { return __builtin_amdgcn_rcpf(x); }

// r12 exp2 formulation + matrix-pipe offload of ALL dense arithmetic:
//  - gate bias + W_ih*x via chained bias-MFMA (A2=[s*W_ih | s*bias], B2=[x;1]),
//    one hoisted zero-C serves every chain (MFMA does not modify C)
//  - fc1/fc2 via MFMA: control head + b1 pre-fused into A (k=5 slot vs bctl's 1.0);
//    bfrag (final h) is already the fc1 B-operand; D->B repack reuses the
//    verified pk16+permlane32_swap pattern (same unit mapping as LSTM)
//  - no LDS, no __syncthreads: wave-autonomous
// Gate rows prescaled by exp2-arg factor (i,f,o: -log2e; g: +2log2e); fc rows
// prescaled by 2log2e so d=exp2(acc)+1 directly. c kept scaled (c'=2log2e*c).
__global__ __launch_bounds__(256, 3) void lstm_mfma_kernel(
    const float* __restrict__ mobility,  // [B,7]
    const float* __restrict__ controls,  // [B,5]
    const float* __restrict__ W_cc, const float* __restrict__ b_cc,
    const float* __restrict__ W_ih, const float* __restrict__ W_hh,
    const float* __restrict__ b_ih, const float* __restrict__ b_hh,
    const float* __restrict__ W1,  const float* __restrict__ b1,
    const float* __restrict__ W2,  const float* __restrict__ b2,
    const float* __restrict__ W3,  const float* __restrict__ b3,
    float* __restrict__ out, int Btot)
{
    const int tid  = threadIdx.x;
    const int lane = tid & 63;
    const int wib  = tid >> 6;
    const int col  = lane & 31;
    const int hi   = lane >> 5;

    const float S2 = 2.0f * LOG2E;

    // ---- LSTM weight fragments (exp2-prescaled), once per block ----
    f16x8 afrag[2], afrag2[2];
    #pragma unroll
    for (int gb = 0; gb < 2; ++gb) {
        const float s = (gb == 0) ? -LOG2E : ((col < 16) ? S2 : -LOG2E);
        const float* wr = W_hh + (gb * 32 + col) * 16 + hi * 8;
        u32x4 aw = { pk16(s * wr[0], s * wr[1]), pk16(s * wr[2], s * wr[3]),
                     pk16(s * wr[4], s * wr[5]), pk16(s * wr[6], s * wr[7]) };
        afrag[gb] = __builtin_bit_cast(f16x8, aw);
        u32x4 a2 = { 0u, 0u, 0u, 0u };
        if (hi == 0) {
            const int gu = gb * 32 + col;
            a2[0] = pk16(s * W_ih[gu], s * (b_ih[gu] + b_hh[gu]));  // k=0: W_ih, k=1: bias
        }
        afrag2[gb] = __builtin_bit_cast(f16x8, a2);
    }

    // ---- fc fragments (rows x 2log2e); control head + b1 fused into a_fc1c ----
    f16x8 a_fc1, a_fc1c, a_fc2;
    {
        u32x4 w1 = {0u,0u,0u,0u}, w1c = {0u,0u,0u,0u}, w2 = {0u,0u,0u,0u};
        if (col < 16) {
            const float* r1 = W1 + col * 19 + hi * 8;     // k = hi*8+e in [0,16)
            w1 = { pk16(S2*r1[0], S2*r1[1]), pk16(S2*r1[2], S2*r1[3]),
                   pk16(S2*r1[4], S2*r1[5]), pk16(S2*r1[6], S2*r1[7]) };
            const float* r2 = W2 + col * 16 + hi * 8;
            w2 = { pk16(S2*r2[0], S2*r2[1]), pk16(S2*r2[2], S2*r2[3]),
                   pk16(S2*r2[4], S2*r2[5]), pk16(S2*r2[6], S2*r2[7]) };
            if (hi == 0) {
                const float wa = W1[col*19+16], wb = W1[col*19+17], wc = W1[col*19+18];
                float cc[5];
                #pragma unroll
                for (int k = 0; k < 5; ++k)
                    cc[k] = wa * W_cc[0*5+k] + wb * W_cc[1*5+k] + wc * W_cc[2*5+k];
                const float bp = b1[col] + wa * b_cc[0] + wb * b_cc[1] + wc * b_cc[2];
                w1c = { pk16(S2*cc[0], S2*cc[1]), pk16(S2*cc[2], S2*cc[3]),
                        pk16(S2*cc[4], S2*bp), 0u };      // k=5 slot = b1' (vs bctl 1.0)
            }
        }
        a_fc1  = __builtin_bit_cast(f16x8, w1);
        a_fc1c = __builtin_bit_cast(f16x8, w1c);
        a_fc2  = __builtin_bit_cast(f16x8, w2);
    }
    const float b3v = b3[0];

    f32x16 fzero;
    #pragma unroll
    for (int r = 0; r < 16; ++r) fzero[r] = 0.0f;

    const v2f one   = { 1.0f, 1.0f };
    const v2f twoL  = { S2, S2 };
    const v2f ntwoL = { -S2, -S2 };

    const int tilesTotal = (Btot + 255) >> 8;      // 4096
    for (int tile = blockIdx.x; tile < tilesTotal; tile += gridDim.x) {
        const int blockRow0 = tile * 256;
        const int r_lo = blockRow0 + wib * 64 + col;
        const int r_hi = r_lo + 32;

        float mlo[7], mhi[7];
        #pragma unroll
        for (int t = 0; t < 7; ++t) { mlo[t] = mobility[(size_t)r_lo * 7 + t]; mhi[t] = mobility[(size_t)r_hi * 7 + t]; }

        float c[2][8];
        #pragma unroll
        for (int rb = 0; rb < 2; ++rb)
            #pragma unroll
            for (int u = 0; u < 8; ++u) c[rb][u] = 0.0f;

        u32x4 bz = { 0u, 0u, 0u, 0u };
        f16x8 bfrag[2];
        bfrag[0] = __builtin_bit_cast(f16x8, bz);
        bfrag[1] = __builtin_bit_cast(f16x8, bz);

        #pragma unroll 1   // rolled: keeps live ranges small (r7 lesson)
        for (int t = 0; t < 7; ++t) {
            #pragma unroll
            for (int rb = 0; rb < 2; ++rb) {
                const float xt = rb ? mhi[t] : mlo[t];

                u32x4 b2w = { 0u, 0u, 0u, 0u };
                if (hi == 0) b2w[0] = pk16(xt, 1.0f);          // B2 = [x ; 1]
                const f16x8 bx = __builtin_bit_cast(f16x8, b2w);

                f32x16 acc0 = __builtin_amdgcn_mfma_f32_32x32x16_f16(afrag2[0], bx, fzero, 0, 0, 0);
                f32x16 a0   = __builtin_amdgcn_mfma_f32_32x32x16_f16(afrag[0], bfrag[rb], acc0, 0, 0, 0);
                f32x16 acc1 = __builtin_amdgcn_mfma_f32_32x32x16_f16(afrag2[1], bx, fzero, 0, 0, 0);
                f32x16 a1   = __builtin_amdgcn_mfma_f32_32x32x16_f16(afrag[1], bfrag[rb], acc1, 0, 0, 0);

                // unit-pair update (r12 formulation)
                float h[8];
                #pragma unroll
                for (int u = 0; u < 8; u += 2) {
                    v2f ea = { fexp2(a0[u]),     fexp2(a0[u + 1]) };   // e^{-gi}
                    v2f ef = { fexp2(a0[u + 8]), fexp2(a0[u + 9]) };   // e^{-gf}
                    v2f eb = { fexp2(a1[u]),     fexp2(a1[u + 1]) };   // e^{2gg}
                    v2f eo = { fexp2(a1[u + 8]), fexp2(a1[u + 9]) };   // e^{-go}
                    v2f pf  = one + ef;
                    v2f pa  = one + ea;
                    v2f den = __builtin_elementwise_fma(pa, eb, pa);   // (1+ea)(eb+1)
                    v2f D   = den * pf;
                    v2f num = __builtin_elementwise_fma(eb, twoL, ntwoL);
                    v2f cv  = { c[rb][u], c[rb][u + 1] };
                    v2f cn  = __builtin_elementwise_fma(cv, den, num * pf);
                    const float rC = frcp(D[0] * D[1]);
                    v2f Dsw = { D[1], D[0] };
                    v2f rCv = { rC, rC };
                    v2f cs  = (cn * Dsw) * rCv;
                    c[rb][u]     = cs[0];
                    c[rb][u + 1] = cs[1];
                    v2f ec = { fexp2(cs[0]), fexp2(cs[1]) };           // e^{2c}
                    v2f ph = one + eo;
                    v2f dh = __builtin_elementwise_fma(ph, ec, ph);    // (1+eo)(ec+1)
                    v2f nh = ec - one;
                    const float rP = frcp(dh[0] * dh[1]);
                    v2f dsw = { dh[1], dh[0] };
                    v2f rPv = { rP, rP };
                    v2f hv  = (nh * dsw) * rPv;
                    h[u]     = hv[0];
                    h[u + 1] = hv[1];
                }
                unsigned q0 = pk16(h[0], h[1]);
                unsigned q1 = pk16(h[2], h[3]);
                unsigned q2 = pk16(h[4], h[5]);
                unsigned q3 = pk16(h[6], h[7]);
                auto s02 = __builtin_amdgcn_permlane32_swap(q0, q2, false, false);
                auto s13 = __builtin_amdgcn_permlane32_swap(q1, q3, false, false);
                u32x4 bw = { s02[0], s13[0], s02[1], s13[1] };
                bfrag[rb] = __builtin_bit_cast(f16x8, bw);
            }
        }

        // ---- fc stage, fully in-wave (no LDS): per-lane b2/W3 gathers ----
        float b2L[8], w3v[8];
        #pragma unroll
        for (int e = 0; e < 8; ++e) {
            const int m = (e & 3) + 8 * (e >> 2) + 4 * hi;    // D-layout row
            b2L[e] = S2 * b2[m];
            w3v[e] = W3[m];
        }

        #pragma unroll
        for (int rb = 0; rb < 2; ++rb) {
            const int grow = rb ? r_hi : r_lo;
            const float* ctl = controls + (size_t)grow * 5;

            u32x4 bcw = { 0u, 0u, 0u, 0u };
            if (hi == 0) {
                bcw[0] = pk16(ctl[0], ctl[1]);
                bcw[1] = pk16(ctl[2], ctl[3]);
                bcw[2] = pk16(ctl[4], 1.0f);                  // k=5 hits b1' slot
            }
            const f16x8 bc = __builtin_bit_cast(f16x8, bcw);

            f32x16 acc = __builtin_amdgcn_mfma_f32_32x32x16_f16(a_fc1c, bc, fzero, 0, 0, 0);
            acc = __builtin_amdgcn_mfma_f32_32x32x16_f16(a_fc1, bfrag[rb], acc, 0, 0, 0);

            // tanh on the 8 valid rows (acc already 2log2e-scaled), pair-merged rcp
            float t1[8];
            #pragma unroll
            for (int r = 0; r < 8; r += 2) {
                const float d0 = fexp2(acc[r])     + 1.0f;
                const float d1 = fexp2(acc[r + 1]) + 1.0f;
                const float rP = frcp(d0 * d1);
                t1[r]     = fmaf(-2.0f * d1, rP, 1.0f);
                t1[r + 1] = fmaf(-2.0f * d0, rP, 1.0f);
            }
            // D->B repack (identical unit mapping as LSTM h)
            unsigned q0 = pk16(t1[0], t1[1]);
            unsigned q1 = pk16(t1[2], t1[3]);
            unsigned q2 = pk16(t1[4], t1[5]);
            unsigned q3 = pk16(t1[6], t1[7]);
            auto s02 = __builtin_amdgcn_permlane32_swap(q0, q2, false, false);
            auto s13 = __builtin_amdgcn_permlane32_swap(q1, q3, false, false);
            u32x4 bw = { s02[0], s13[0], s02[1], s13[1] };
            const f16x8 bt1 = __builtin_bit_cast(f16x8, bw);

            f32x16 acc2 = __builtin_amdgcn_mfma_f32_32x32x16_f16(a_fc2, bt1, fzero, 0, 0, 0);

            float t2[8];
            #pragma unroll
            for (int r = 0; r < 8; r += 2) {
                const float d0 = fexp2(acc2[r]     + b2L[r])     + 1.0f;
                const float d1 = fexp2(acc2[r + 1] + b2L[r + 1]) + 1.0f;
                const float rP = frcp(d0 * d1);
                t2[r]     = fmaf(-2.0f * d1, rP, 1.0f);
                t2[r + 1] = fmaf(-2.0f * d0, rP, 1.0f);
            }

            float dot = t2[0] * w3v[0];
            #pragma unroll
            for (int e = 1; e < 8; ++e) dot = fmaf(t2[e], w3v[e], dot);
            const float tot = dot + __shfl_xor(dot, 32);      // pair-half sum
            const float res = fmaxf(tot + b3v, 0.0f);
            if (hi == 0 && grow < Btot) out[grow] = res;
        }
    }
}

extern "C" void kernel_launch(void* const* d_in, const int* in_sizes, int n_in,
                              void* d_out, int out_size, void* d_ws, size_t ws_size,
                              hipStream_t stream) {
    const float* mobility = (const float*)d_in[0];
    const float* controls = (const float*)d_in[1];
    // d_in[2] = last : unused by the reference
    const float* W_cc = (const float*)d_in[3];
    const float* b_cc = (const float*)d_in[4];
    const float* W_ih = (const float*)d_in[5];
    const float* W_hh = (const float*)d_in[6];
    const float* b_ih = (const float*)d_in[7];
    const float* b_hh = (const float*)d_in[8];
    const float* W1   = (const float*)d_in[9];
    const float* b1   = (const float*)d_in[10];
    const float* W2   = (const float*)d_in[11];
    const float* b2   = (const float*)d_in[12];
    const float* W3   = (const float*)d_in[13];
    const float* b3   = (const float*)d_in[14];
    float* out = (float*)d_out;

    const int Btot  = in_sizes[0] / 7;              // 1048576
    const int tiles = (Btot + 255) / 256;           // 4096
    const int grid  = tiles < 1024 ? tiles : 1024;  // 4 tiles/block

    lstm_mfma_kernel<<<grid, 256, 0, stream>>>(
        mobility, controls, W_cc, b_cc, W_ih, W_hh, b_ih, b_hh,
        W1, b1, W2, b2, W3, b3, out, Btot);
}